// Round 8
// baseline (225.824 us; speedup 1.0000x reference)
//
#include <hip/hip_runtime.h>
#include <hip/hip_bf16.h>

using bf16 = __hip_bfloat16;
typedef __attribute__((ext_vector_type(8))) short short8;
typedef __attribute__((ext_vector_type(4))) short s4v;
typedef __attribute__((ext_vector_type(4))) float float4v;
typedef __attribute__((ext_vector_type(4))) float f32x4;
typedef __attribute__((ext_vector_type(16))) float f32x16;
typedef __attribute__((ext_vector_type(4))) int i32x4;

#define MFMA16(a, b, c) __builtin_amdgcn_mfma_f32_16x16x32_bf16((a), (b), (c), 0, 0, 0)
#define MFMA32(a, b, c) __builtin_amdgcn_mfma_f32_32x32x16_bf16((a), (b), (c), 0, 0, 0)

// async global->LDS, 16B per lane, dest = wave-uniform base + lane*16
#define GLD_LDS16(g, l)                                            \
    __builtin_amdgcn_global_load_lds(                              \
        (const __attribute__((address_space(1))) void*)(g),        \
        (__attribute__((address_space(3))) void*)(l), 16, 0, 0)

constexpr int Bc = 2;
constexpr int Sc = 2048;
constexpr int Hc = 16;
constexpr int DKc = 64;
constexpr int Dc = 1024;
constexpr size_t MEG = 1024 * 1024;

union BFU { bf16 h; short s; };
union PKU { i32x4 i; short8 s; };

__device__ inline short bfbits(float f) {
    BFU u; u.h = __float2bfloat16(f); return u.s;
}

__device__ inline float bits2f(short s) {
    BFU u; u.s = s; return __bfloat162float(u.h);
}

// packed f32x2 -> bf16x2 (low = a, high = b); RNE, single VOP3
__device__ inline unsigned cvtpk(float a, float b) {
    unsigned r;
    asm("v_cvt_pk_bf16_f32 %0, %1, %2" : "=v"(r) : "v"(a), "v"(b));
    return r;
}

__device__ inline short8 load_cvt8(const float* __restrict__ p) {
    f32x4 a = *(const f32x4*)p;
    f32x4 b = *(const f32x4*)(p + 4);
    short8 r;
    r[0] = bfbits(a[0]); r[1] = bfbits(a[1]); r[2] = bfbits(a[2]); r[3] = bfbits(a[3]);
    r[4] = bfbits(b[0]); r[5] = bfbits(b[1]); r[6] = bfbits(b[2]); r[7] = bfbits(b[3]);
    return r;
}

// ---------------------------------------------------------------------------
// One-shot fp32 -> bf16 conversion of x, Wq, Wk, Wv, Wo (8M elems) into ws.
// ---------------------------------------------------------------------------
__global__ __launch_bounds__(256) void cvt_kernel(
    const float* __restrict__ x, const float* __restrict__ Wq,
    const float* __restrict__ Wk, const float* __restrict__ Wv,
    const float* __restrict__ Wo, bf16* __restrict__ dst)
{
    const size_t i = ((size_t)blockIdx.x * 256 + threadIdx.x) * 8;
    const float* s;
    if      (i < 4 * MEG) s = x  + i;
    else if (i < 5 * MEG) s = Wq + (i - 4 * MEG);
    else if (i < 6 * MEG) s = Wk + (i - 5 * MEG);
    else if (i < 7 * MEG) s = Wv + (i - 6 * MEG);
    else                  s = Wo + (i - 7 * MEG);
    *(short8*)(dst + i) = load_cvt8(s);
}

// ---------------------------------------------------------------------------
// Fused QKV projection, m97-style BK=32. grid (24, 32): sel = bx>>3.
// Q pre-scaled by (1/8)*log2e, row-major (b,h,s,d).
// K and V are written in MFMA-FRAGMENT-MAJOR order for the 32x32x16 attn:
//   K frag elem: [bh][s>>6][ (kv=(s>>5)&1)*4 + (d>>4) ][ (s&31)+32*((d>>3)&1) ][ d&7 ]
//   V frag elem: [bh][s>>6][ (dv=d>>5)*4 + ((s>>4)&3) ][ (d&31)+32*((s>>3)&1) ][ s&7 ]
// so attn staging is contiguous 1KB chunks and ds_read_b128 = base+lane*16
// (conflict-free, no swizzle math).
// ---------------------------------------------------------------------------
__global__ __launch_bounds__(256) void qkv_gemm_kernel(
    const bf16* __restrict__ x,
    const bf16* __restrict__ Wq, const float* __restrict__ bq,
    const bf16* __restrict__ Wk, const float* __restrict__ bk,
    const bf16* __restrict__ Wv, const float* __restrict__ bv,
    bf16* __restrict__ q_ws, bf16* __restrict__ k_ws, bf16* __restrict__ v_ws)
{
    constexpr int BM = 128, BN = 128, BK = 32;
    __shared__ __align__(16) bf16 sA[BM * BK];
    __shared__ __align__(16) bf16 sB[BN * BK];

    const int bx = blockIdx.x;
    const int sel = bx >> 3;               // 0=Q 1=K 2=V
    const int n0 = (bx & 7) * BN;
    const int m0 = blockIdx.y * BM;

    const bf16* __restrict__ Wsel = (sel == 0) ? Wq : ((sel == 1) ? Wk : Wv);
    const float* __restrict__ bsel = (sel == 0) ? bq : ((sel == 1) ? bk : bv);

    const int t = threadIdx.x;
    const int lane = t & 63;
    const int wave = t >> 6;
    const int ln = lane & 15;
    const int qd = lane >> 4;
    const int wm = (wave >> 1) * 64;
    const int wn = (wave & 1) * 64;

    const int gr = lane >> 2;              // 0..15: row within 16-row chunk
    const int gc = (lane & 3) * 8;         // 0,8,16,24

    float4v acc[4][4];
#pragma unroll
    for (int i = 0; i < 4; i++)
#pragma unroll
        for (int j = 0; j < 4; j++) acc[i][j] = (float4v)0.0f;

    for (int kk = 0; kk < Dc; kk += BK) {
        __syncthreads();
#pragma unroll
        for (int cc = 0; cc < 2; cc++) {
            const int c = wave * 2 + cc;
            GLD_LDS16(x    + (size_t)(m0 + c * 16 + gr) * Dc + kk + gc, &sA[c * 512]);
            GLD_LDS16(Wsel + (size_t)(n0 + c * 16 + gr) * Dc + kk + gc, &sB[c * 512]);
        }
        __syncthreads();

        short8 af[4], wf[4];
#pragma unroll
        for (int i = 0; i < 4; i++)
            af[i] = *(const short8*)&sA[(wm + i * 16 + ln) * BK + qd * 8];
#pragma unroll
        for (int j = 0; j < 4; j++)
            wf[j] = *(const short8*)&sB[(wn + j * 16 + ln) * BK + qd * 8];
#pragma unroll
        for (int i = 0; i < 4; i++)
#pragma unroll
            for (int j = 0; j < 4; j++)
                acc[i][j] = MFMA16(af[i], wf[j], acc[i][j]);
    }

    constexpr float QSCALE = 0.125f * 1.44269504088896f;

#pragma unroll
    for (int j = 0; j < 4; j++) {
        const int n = n0 + wn + j * 16 + ln;
        const float bias = bsel[n];
        const int h_ = n >> 6, d_ = n & 63;
#pragma unroll
        for (int i = 0; i < 4; i++) {
            const int mbase = m0 + wm + i * 16 + qd * 4;
            const int b_ = mbase >> 11, s0_ = mbase & 2047;
            if (sel == 2) {                // V frag-order: 4 s-contig -> 8B store
                const int dv_ = d_ >> 5, cV = d_ & 31;
                const int ktg = s0_ >> 6, ksl = (s0_ >> 4) & 3;
                const int hiV = (s0_ >> 3) & 1, i0 = s0_ & 7;
                s4v pk;
#pragma unroll
                for (int r = 0; r < 4; r++)
                    pk[r] = bfbits(acc[i][j][r] + bias);
                *(s4v*)&v_ws[(size_t)(b_ * Hc + h_) * Sc * DKc + ktg * 4096
                             + (dv_ * 4 + ksl) * 512 + (cV + 32 * hiV) * 8 + i0] = pk;
            } else if (sel == 1) {         // K frag-order: scalar stores
                const int ks_ = d_ >> 4, hiK = (d_ >> 3) & 1, ii = d_ & 7;
#pragma unroll
                for (int r = 0; r < 4; r++) {
                    const int s_ = s0_ + r;
                    const int ktg = s_ >> 6, kv = (s_ >> 5) & 1, cK = s_ & 31;
                    k_ws[(size_t)(b_ * Hc + h_) * Sc * DKc + ktg * 4096
                         + (kv * 4 + ks_) * 512 + (cK + 32 * hiK) * 8 + ii] =
                        __float2bfloat16(acc[i][j][r] + bias);
                }
            } else {                       // Q row-major, pre-scaled
#pragma unroll
                for (int r = 0; r < 4; r++) {
                    const int s_ = s0_ + r;
                    q_ws[(((size_t)(b_ * Hc + h_)) * Sc + s_) * DKc + d_] =
                        __float2bfloat16((acc[i][j][r] + bias) * QSCALE);
                }
            }
        }
    }
}

// ---------------------------------------------------------------------------
// Flash attention v9 (UNCHANGED from Round 7 — holds the measurement):
// 32x32 MFMA + in-register softmax + frag-major K/V staging. 4 waves x 32
// qrows; split-S z=2; grid (32,16,2)=1024 -> 4 blocks/CU (LDS 32KB).
// ---------------------------------------------------------------------------
__global__ __launch_bounds__(256, 4) void attn_kernel(
    const bf16* __restrict__ q_ws, const bf16* __restrict__ kf_ws,
    const bf16* __restrict__ vf_ws, bf16* __restrict__ po0,
    bf16* __restrict__ po1, float* __restrict__ l_ws)
{
    constexpr int NKT = 16;                // 16 ktiles x 64 keys = 1024/split
    __shared__ __align__(16) bf16 sK[2][8 * 512];   // [buf][kv*4+ks][lane*8]
    __shared__ __align__(16) bf16 sV[2][8 * 512];   // [buf][dv*4+ksl][lane*8]

    const int bh = blockIdx.x;
    const int qt = blockIdx.y;
    const int sp = blockIdx.z;
    const int t = threadIdx.x;
    const int lane = t & 63;
    const int wave = t >> 6;               // 0..3
    const int c = lane & 31;
    const int hi = lane >> 5;

    const bf16* __restrict__ Qbase = q_ws + (size_t)bh * Sc * DKc
                                   + (size_t)(qt * 128 + wave * 32) * DKc;
    const bf16* __restrict__ KF = kf_ws + ((size_t)bh * Sc + sp * 1024) * DKc;
    const bf16* __restrict__ VF = vf_ws + ((size_t)bh * Sc + sp * 1024) * DKc;

    // Q B-frags, loop-invariant (16 VGPRs): B[n=qrow=c][k=ks*16+hi*8+i]
    short8 qf[4];
#pragma unroll
    for (int ks = 0; ks < 4; ks++)
        qf[ks] = *(const short8*)(Qbase + (size_t)c * DKc + ks * 16 + hi * 8);

    // ones B-frag: B[n][k] = 1 iff n==0 (denominator column)
    short8 ones8;
    {
        const short ob = (c == 0) ? (short)0x3F80 : (short)0;
#pragma unroll
        for (int i = 0; i < 8; i++) ones8[i] = ob;
    }

    auto stage = [&](int buf, int kt2) {
#pragma unroll
        for (int cc = 0; cc < 4; cc++) {
            const int cid = (wave << 2) + cc;      // 0..15, wave-uniform
            if (cid < 8)
                GLD_LDS16(KF + (size_t)kt2 * 4096 + cid * 512 + lane * 8,
                          &sK[buf][cid * 512]);
            else
                GLD_LDS16(VF + (size_t)kt2 * 4096 + (cid - 8) * 512 + lane * 8,
                          &sV[buf][(cid - 8) * 512]);
        }
    };

    f32x16 oacc0 = (f32x16)0.0f;           // O[:, d = 0..31]
    f32x16 oacc1 = (f32x16)0.0f;           // O[:, d = 32..63]
    f32x16 den   = (f32x16)0.0f;           // col 0 = row sums

    stage(0, 0);

    for (int kt = 0; kt < NKT; kt++) {
        const int cur = kt & 1;
        __syncthreads();                   // drains vmcnt: buf[cur] ready
        if (kt + 1 < NKT) stage(cur ^ 1, kt + 1);

#pragma unroll
        for (int kv = 0; kv < 2; kv++) {
            // S^T tile: A=K[key], B=Q[qrow]; lane holds qrow=c, keys 8q+4hi+t
            f32x16 sacc = (f32x16)0.0f;
            __builtin_amdgcn_s_setprio(1);
#pragma unroll
            for (int ks = 0; ks < 4; ks++) {
                const short8 kfr = *(const short8*)
                    &sK[cur][(kv * 4 + ks) * 512 + lane * 8];
                sacc = MFMA32(kfr, qf[ks], sacc);
            }
            __builtin_amdgcn_s_setprio(0);

            // P = exp2(S^T): 16 f32 -> 8 packed bf16 dwords; swap half-rows
            unsigned s0[4][2], sw[4][2];
#pragma unroll
            for (int q = 0; q < 4; q++)
#pragma unroll
                for (int j = 0; j < 2; j++)
                    s0[q][j] = cvtpk(exp2f(sacc[q * 4 + j * 2]),
                                     exp2f(sacc[q * 4 + j * 2 + 1]));
#pragma unroll
            for (int q = 0; q < 4; q++)
#pragma unroll
                for (int j = 0; j < 2; j++)
                    sw[q][j] = (unsigned)__shfl_xor((int)s0[q][j], 32, 64);

            // PV: A[m=qrow][k=key] built in-lane; B=V^T frag from LDS
            __builtin_amdgcn_s_setprio(1);
#pragma unroll
            for (int m = 0; m < 2; m++) {  // kslice = kv*2+m (16 keys each)
                PKU u;
                u.i[0] = (int)(hi ? sw[2 * m + 1][0] : s0[2 * m][0]);
                u.i[1] = (int)(hi ? sw[2 * m + 1][1] : s0[2 * m][1]);
                u.i[2] = (int)(hi ? s0[2 * m + 1][0] : sw[2 * m][0]);
                u.i[3] = (int)(hi ? s0[2 * m + 1][1] : sw[2 * m][1]);
                const short8 ap = u.s;
                const int ksl = kv * 2 + m;
                const short8 vf0 = *(const short8*)
                    &sV[cur][(0 + ksl) * 512 + lane * 8];
                const short8 vf1 = *(const short8*)
                    &sV[cur][(4 + ksl) * 512 + lane * 8];
                oacc0 = MFMA32(ap, vf0, oacc0);
                oacc1 = MFMA32(ap, vf1, oacc1);
                den   = MFMA32(ap, ones8, den);
            }
            __builtin_amdgcn_s_setprio(0);
        }
    }

    // Epilogue: den col 0 lives in lanes c==0 (both hi halves).
    const int b_ = bh >> 4, h_ = bh & 15;
    bf16* __restrict__ po = sp ? po1 : po0;
    if (c == 0) {
#pragma unroll
        for (int r = 0; r < 16; r++) {
            const int qrow = (r & 3) + 8 * (r >> 2) + 4 * hi;
            l_ws[(size_t)(sp * 32 + bh) * Sc + qt * 128 + wave * 32 + qrow] =
                den[r];
        }
    }
#pragma unroll
    for (int r = 0; r < 16; r++) {
        const float l = __shfl(den[r], lane & 32, 64);  // lane (0, hi)
        const float inv = 1.0f / l;
        const int qrow = (r & 3) + 8 * (r >> 2) + 4 * hi;
        const int s_ = qt * 128 + wave * 32 + qrow;
        const size_t rowb = (((size_t)(b_ * Sc + s_)) * Hc + h_) * DKc;
        po[rowb + c]      = __float2bfloat16(oacc0[r] * inv);
        po[rowb + 32 + c] = __float2bfloat16(oacc1[r] * inv);
    }
}

// ---------------------------------------------------------------------------
// Output projection v10: combine FUSED into A-staging + 2 blocks/CU.
//   - BM=128, BN=64, BK=32 -> grid (16,32) = 512 blocks = 2/CU (v9's 256 =
//     1/CU left the barrier drain fully exposed, nothing co-resident).
//   - A-tile = w0*O0 + w1*O1 built in registers during staging (deletes the
//     combine kernel + its 24 MB round trip). Within a BK=32 slice h = kk>>6
//     is constant, so per-row weights are two L2-hot scalar loads.
//   - T14 issue-early: next slice's po0/po1 loads issue before this slice's
//     math, hiding global latency under MFMA+math.
// ---------------------------------------------------------------------------
__global__ __launch_bounds__(256) void out_gemm_kernel(
    const bf16* __restrict__ po0, const bf16* __restrict__ po1,
    const float* __restrict__ l_ws, const bf16* __restrict__ Wo,
    const float* __restrict__ bo, float* __restrict__ out)
{
    constexpr int BM = 128, BN = 64, BK = 32;
    __shared__ __align__(16) bf16 sA[BM * BK];   // 8 KB
    __shared__ __align__(16) bf16 sB[BN * BK];   // 4 KB

    const int n0 = blockIdx.x * BN;
    const int m0 = blockIdx.y * BM;

    const int t = threadIdx.x;
    const int lane = t & 63;
    const int wave = t >> 6;
    const int ln = lane & 15;
    const int qd = lane >> 4;
    const int wm = (wave >> 1) * 64;
    const int wn = (wave & 1) * 32;

    const int gr = lane >> 2;              // B-staging row within 16-row chunk
    const int gc = (lane & 3) * 8;

    const int ar = t >> 2;                 // A-staging: rows ar, ar+64
    const int ac = (t & 3) * 8;            // col group

    float4v acc[4][2];
#pragma unroll
    for (int i = 0; i < 4; i++)
#pragma unroll
        for (int j = 0; j < 2; j++) acc[i][j] = (float4v)0.0f;

    short8 a0[2], a1[2];
    auto loadA = [&](int kk) {
#pragma unroll
        for (int L = 0; L < 2; L++) {
            const size_t row = (size_t)(m0 + L * 64 + ar);
            a0[L] = *(const short8*)&po0[row * Dc + kk + ac];
            a1[L] = *(const short8*)&po1[row * Dc + kk + ac];
        }
    };
    loadA(0);

    for (int kk = 0; kk < Dc; kk += BK) {
        __syncthreads();                   // prior-iter LDS reads done
        // B-tile async (4 chunks of 16 rows; wave w stages chunk w)
        GLD_LDS16(Wo + (size_t)(n0 + wave * 16 + gr) * Dc + kk + gc,
                  &sB[wave * 512]);
        // snapshot current A regs, then issue next slice's loads (T14)
        const short8 c0_0 = a0[0], c0_1 = a0[1];
        const short8 c1_0 = a1[0], c1_1 = a1[1];
        if (kk + BK < Dc) loadA(kk + BK);
        // fused combine: sA = w0*O0 + w1*O1 (h constant within slice)
        const int h = kk >> 6;
#pragma unroll
        for (int L = 0; L < 2; L++) {
            const int row = m0 + L * 64 + ar;
            const int b_ = row >> 11, s_ = row & 2047;
            const int bhl = b_ * Hc + h;
            const float l0 = l_ws[(size_t)bhl * Sc + s_];
            const float l1 = l_ws[(size_t)(32 + bhl) * Sc + s_];
            const float inv = 1.0f / (l0 + l1);
            const float w0 = l0 * inv, w1 = l1 * inv;
            const short8 ca = L ? c0_1 : c0_0;
            const short8 cb = L ? c1_1 : c1_0;
            short8 o;
#pragma unroll
            for (int e = 0; e < 8; e++)
                o[e] = bfbits(bits2f(ca[e]) * w0 + bits2f(cb[e]) * w1);
            *(short8*)&sA[(L * 64 + ar) * BK + ac] = o;
        }
        __syncthreads();                   // drains B-GLD + A ds_writes

        short8 af[4], wf[2];
#pragma unroll
        for (int i = 0; i < 4; i++)
            af[i] = *(const short8*)&sA[(wm + i * 16 + ln) * BK + qd * 8];
#pragma unroll
        for (int j = 0; j < 2; j++)
            wf[j] = *(const short8*)&sB[(wn + j * 16 + ln) * BK + qd * 8];
#pragma unroll
        for (int i = 0; i < 4; i++)
#pragma unroll
            for (int j = 0; j < 2; j++)
                acc[i][j] = MFMA16(af[i], wf[j], acc[i][j]);
    }

#pragma unroll
    for (int j = 0; j < 2; j++) {
        const int n = n0 + wn + j * 16 + ln;
        const float bias = bo[n];
#pragma unroll
        for (int i = 0; i < 4; i++) {
            const int mbase = m0 + wm + i * 16 + qd * 4;
#pragma unroll
            for (int r = 0; r < 4; r++) {
                const int m = mbase + r;
                out[(size_t)m * Dc + n] = acc[i][j][r] + bias;
            }
        }
    }
}

// ---------------------------------------------------------------------------
extern "C" void kernel_launch(void* const* d_in, const int* in_sizes, int n_in,
                              void* d_out, int out_size, void* d_ws, size_t ws_size,
                              hipStream_t stream)
{
    const float* x  = (const float*)d_in[0];
    const float* Wq = (const float*)d_in[1];
    const float* bq = (const float*)d_in[2];
    const float* Wk = (const float*)d_in[3];
    const float* bk = (const float*)d_in[4];
    const float* Wv = (const float*)d_in[5];
    const float* bv = (const float*)d_in[6];
    const float* Wo = (const float*)d_in[7];
    const float* bo = (const float*)d_in[8];
    float* out = (float*)d_out;

    bf16* base  = (bf16*)d_ws;
    bf16* q_ws  = base;                      // (b,h,s,d), pre-scaled
    bf16* k_ws  = base + 4 * MEG;            // K frag-major (see qkv_gemm)
    bf16* v_ws  = base + 8 * MEG;            // V frag-major (see qkv_gemm)
    bf16* ao_ws = base + 12 * MEG;           // (b,s,h,d) partial O of split 0
    bf16* xb    = base + 16 * MEG;           // bf16 inputs; reused as split-1 partial
    bf16* po1   = xb;                        // (b,s,h,d) partial O of split 1 (8 MB)
    bf16* wqb   = base + 20 * MEG;           // reused as l_ws after qkv_gemm
    float* l_ws = (float*)wqb;               // [split][bh][s] denominators (512 KB)
    bf16* wkb   = base + 21 * MEG;
    bf16* wvb   = base + 22 * MEG;
    bf16* wob   = base + 23 * MEG;

    cvt_kernel<<<dim3(4096), 256, 0, stream>>>(x, Wq, Wk, Wv, Wo, xb);
    qkv_gemm_kernel<<<dim3(24, 32), 256, 0, stream>>>(
        xb, wqb, bq, wkb, bk, wvb, bv, q_ws, k_ws, v_ws);
    attn_kernel<<<dim3(32, 16, 2), 256, 0, stream>>>(
        q_ws, k_ws, v_ws, ao_ws, po1, l_ws);
    out_gemm_kernel<<<dim3(16, 32), 256, 0, stream>>>(
        ao_ws, po1, l_ws, wob, bo, out);
}

// Round 9
// 200.890 us; speedup vs baseline: 1.1241x; 1.1241x over previous
//
#include <hip/hip_runtime.h>
#include <hip/hip_bf16.h>

using bf16 = __hip_bfloat16;
typedef __attribute__((ext_vector_type(8))) short short8;
typedef __attribute__((ext_vector_type(4))) short s4v;
typedef __attribute__((ext_vector_type(4))) float float4v;
typedef __attribute__((ext_vector_type(4))) float f32x4;

#define MFMA16(a, b, c) __builtin_amdgcn_mfma_f32_16x16x32_bf16((a), (b), (c), 0, 0, 0)

// async global->LDS, 16B per lane, dest = wave-uniform base + lane*16
#define GLD_LDS16(g, l)                                            \
    __builtin_amdgcn_global_load_lds(                              \
        (const __attribute__((address_space(1))) void*)(g),        \
        (__attribute__((address_space(3))) void*)(l), 16, 0, 0)

constexpr int Bc = 2;
constexpr int Sc = 2048;
constexpr int Hc = 16;
constexpr int DKc = 64;
constexpr int Dc = 1024;
constexpr size_t MEG = 1024 * 1024;

union BFU { bf16 h; short s; };

__device__ inline short bfbits(float f) {
    BFU u; u.h = __float2bfloat16(f); return u.s;
}

__device__ inline short8 load_cvt8(const float* __restrict__ p) {
    f32x4 a = *(const f32x4*)p;
    f32x4 b = *(const f32x4*)(p + 4);
    short8 r;
    r[0] = bfbits(a[0]); r[1] = bfbits(a[1]); r[2] = bfbits(a[2]); r[3] = bfbits(a[3]);
    r[4] = bfbits(b[0]); r[5] = bfbits(b[1]); r[6] = bfbits(b[2]); r[7] = bfbits(b[3]);
    return r;
}

// ---------------------------------------------------------------------------
// One-shot fp32 -> bf16 conversion of x, Wq, Wk, Wv, Wo (8M elems) into ws.
// ---------------------------------------------------------------------------
__global__ __launch_bounds__(256) void cvt_kernel(
    const float* __restrict__ x, const float* __restrict__ Wq,
    const float* __restrict__ Wk, const float* __restrict__ Wv,
    const float* __restrict__ Wo, bf16* __restrict__ dst)
{
    const size_t i = ((size_t)blockIdx.x * 256 + threadIdx.x) * 8;
    const float* s;
    if      (i < 4 * MEG) s = x  + i;
    else if (i < 5 * MEG) s = Wq + (i - 4 * MEG);
    else if (i < 6 * MEG) s = Wk + (i - 5 * MEG);
    else if (i < 7 * MEG) s = Wv + (i - 6 * MEG);
    else                  s = Wo + (i - 7 * MEG);
    *(short8*)(dst + i) = load_cvt8(s);
}

// ---------------------------------------------------------------------------
// Fused QKV projection, m97-style BK=32. grid (24, 32): sel = bx>>3,
// ntile = bx&7. Q pre-scaled by (1/8)*log2e. V^T stores packed to 8B.
// ---------------------------------------------------------------------------
__global__ __launch_bounds__(256) void qkv_gemm_kernel(
    const bf16* __restrict__ x,
    const bf16* __restrict__ Wq, const float* __restrict__ bq,
    const bf16* __restrict__ Wk, const float* __restrict__ bk,
    const bf16* __restrict__ Wv, const float* __restrict__ bv,
    bf16* __restrict__ q_ws, bf16* __restrict__ k_ws, bf16* __restrict__ v_ws)
{
    constexpr int BM = 128, BN = 128, BK = 32;
    __shared__ __align__(16) bf16 sA[BM * BK];
    __shared__ __align__(16) bf16 sB[BN * BK];

    const int bx = blockIdx.x;
    const int sel = bx >> 3;               // 0=Q 1=K 2=V
    const int n0 = (bx & 7) * BN;
    const int m0 = blockIdx.y * BM;

    const bf16* __restrict__ Wsel = (sel == 0) ? Wq : ((sel == 1) ? Wk : Wv);
    const float* __restrict__ bsel = (sel == 0) ? bq : ((sel == 1) ? bk : bv);

    const int t = threadIdx.x;
    const int lane = t & 63;
    const int wave = t >> 6;
    const int ln = lane & 15;
    const int qd = lane >> 4;
    const int wm = (wave >> 1) * 64;
    const int wn = (wave & 1) * 64;

    const int gr = lane >> 2;              // 0..15: row within 16-row chunk
    const int gc = (lane & 3) * 8;         // 0,8,16,24

    float4v acc[4][4];
#pragma unroll
    for (int i = 0; i < 4; i++)
#pragma unroll
        for (int j = 0; j < 4; j++) acc[i][j] = (float4v)0.0f;

    for (int kk = 0; kk < Dc; kk += BK) {
        __syncthreads();
#pragma unroll
        for (int cc = 0; cc < 2; cc++) {
            const int c = wave * 2 + cc;
            GLD_LDS16(x    + (size_t)(m0 + c * 16 + gr) * Dc + kk + gc, &sA[c * 512]);
            GLD_LDS16(Wsel + (size_t)(n0 + c * 16 + gr) * Dc + kk + gc, &sB[c * 512]);
        }
        __syncthreads();

        short8 af[4], wf[4];
#pragma unroll
        for (int i = 0; i < 4; i++)
            af[i] = *(const short8*)&sA[(wm + i * 16 + ln) * BK + qd * 8];
#pragma unroll
        for (int j = 0; j < 4; j++)
            wf[j] = *(const short8*)&sB[(wn + j * 16 + ln) * BK + qd * 8];
#pragma unroll
        for (int i = 0; i < 4; i++)
#pragma unroll
            for (int j = 0; j < 4; j++)
                acc[i][j] = MFMA16(af[i], wf[j], acc[i][j]);
    }

    constexpr float QSCALE = 0.125f * 1.44269504088896f;

#pragma unroll
    for (int j = 0; j < 4; j++) {
        const int n = n0 + wn + j * 16 + ln;
        const float bias = bsel[n];
        const int h_ = n >> 6, d_ = n & 63;
#pragma unroll
        for (int i = 0; i < 4; i++) {
            const int mbase = m0 + wm + i * 16 + qd * 4;
            if (sel == 2) {                // V^T: 4 s-contiguous -> one 8B store
                const int b_ = mbase >> 11, s_ = mbase & 2047;
                s4v pk;
#pragma unroll
                for (int r = 0; r < 4; r++)
                    pk[r] = bfbits(acc[i][j][r] + bias);
                *(s4v*)&v_ws[(((size_t)(b_ * Hc + h_)) * DKc + d_) * Sc + s_] = pk;
            } else {
#pragma unroll
                for (int r = 0; r < 4; r++) {
                    const int m = mbase + r;
                    const int b_ = m >> 11, s_ = m & 2047;
                    float v = acc[i][j][r] + bias;
                    if (sel == 0) v *= QSCALE;
                    const bf16 o = __float2bfloat16(v);
                    if (sel == 0)
                        q_ws[(((size_t)(b_ * Hc + h_)) * Sc + s_) * DKc + d_] = o;
                    else
                        k_ws[(((size_t)(b_ * Hc + h_)) * Sc + s_) * DKc + d_] = o;
                }
            }
        }
    }
}

// ---------------------------------------------------------------------------
// Flash attention v7 (UNCHANGED — proven 65.6 us, 0 bank conflicts):
// 8 waves x 16 q-rows, Q in registers, sP stride 76 (conflict-free),
// xor-swizzled async dbuf K/V, ONE barrier/ktile, swapped-operand QK^T,
// ones-column denominator, setprio around MFMA clusters. grid (32,16), 512.
// ---------------------------------------------------------------------------
__global__ __launch_bounds__(512, 4) void attn_kernel(
    const bf16* __restrict__ q_ws, const bf16* __restrict__ k_ws,
    const bf16* __restrict__ v_ws, bf16* __restrict__ ao_ws)
{
    constexpr int LQP = 76;  // short row stride for sP (152 B, conflict-free)
    __shared__ __align__(16) bf16 sK[2][64 * 64];    // swizzled dbuf
    __shared__ __align__(16) bf16 sV[2][64 * 64];    // V^T [d][key], swizzled dbuf
    __shared__ __align__(16) short sP[8][16 * LQP];  // per-wave P [qrow][key]

    const int bh = blockIdx.x;
    const int qt = blockIdx.y;
    const int t = threadIdx.x;
    const int lane = t & 63;
    const int wave = t >> 6;               // 0..7
    const int ln = lane & 15;
    const int qd = lane >> 4;
    short* const sPw = sP[wave];

    const bf16* __restrict__ Qbase = q_ws + (size_t)bh * Sc * DKc + qt * 128 * DKc;
    const bf16* __restrict__ Kbase = k_ws + (size_t)bh * Sc * DKc;
    const bf16* __restrict__ Vbase = v_ws + (size_t)bh * DKc * Sc;

    const int rloc = lane >> 3;            // 0..7 row within 8-row chunk
    const int blk = lane & 7;              // LDS 16B-block index

    // Q B-frags direct global->register, loop-invariant (8 VGPRs).
    // lane holds Q[qrow = wave*16 + ln][k = ks*32 + qd*8 .. +7]
    short8 qf[2];
#pragma unroll
    for (int ks = 0; ks < 2; ks++)
        qf[ks] = *(const short8*)
            (Qbase + (size_t)(wave * 16 + ln) * DKc + ks * 32 + qd * 8);

    {   // stage K/V tile 0 async: 8 chunks each, one per wave
        const int row = wave * 8 + rloc;
        const int gb = blk ^ (row & 7);
        GLD_LDS16(Kbase + (size_t)row * DKc + gb * 8, &sK[0][wave * 512]);
        GLD_LDS16(Vbase + (size_t)row * Sc + gb * 8, &sV[0][wave * 512]);
    }

    // constant ones B-frag: B[n=64+ln][k]=1 iff ln==0 (denominator column)
    short8 ones8;
    {
        const short ob = (ln == 0) ? (short)0x3F80 : (short)0;
#pragma unroll
        for (int i = 0; i < 8; i++) ones8[i] = ob;
    }

    float4v oacc[5];
#pragma unroll
    for (int j = 0; j < 5; j++) oacc[j] = (float4v)0.0f;

    for (int kt = 0; kt < Sc / 64; kt++) {
        const int cur = kt & 1;
        __syncthreads();   // drains vmcnt: buf[cur] ready; prior reads done
        if (kt + 1 < Sc / 64) {    // prefetch next tile into the other buffer
            const int nxt = (kt + 1) & 1;
            const int row = wave * 8 + rloc;
            const int gb = blk ^ (row & 7);
            GLD_LDS16(Kbase + (size_t)((kt + 1) * 64 + row) * DKc + gb * 8,
                      &sK[nxt][wave * 512]);
            GLD_LDS16(Vbase + (size_t)row * Sc + (kt + 1) * 64 + gb * 8,
                      &sV[nxt][wave * 512]);
        }

        // S^T = K Q^T: A=K[m=key], B=Q[n=qrow]; C col=qrow(ln), row=key(qd*4+r)
        float4v sacc[4];
#pragma unroll
        for (int j = 0; j < 4; j++) sacc[j] = (float4v)0.0f;
        __builtin_amdgcn_s_setprio(1);
#pragma unroll
        for (int ks = 0; ks < 2; ks++) {
#pragma unroll
            for (int j = 0; j < 4; j++) {
                const int row = j * 16 + ln;
                const short8 ak = *(const short8*)
                    &sK[cur][row * 64 + (((ks * 4 + qd) ^ (row & 7)) << 3)];
                sacc[j] = MFMA16(ak, qf[ks], sacc[j]);
            }
        }
        __builtin_amdgcn_s_setprio(0);

        // P = exp2(S^T) -> sP [qrow][key]: lane holds qrow=ln, keys 4-contig.
#pragma unroll
        for (int j = 0; j < 4; j++) {
            s4v pk;
#pragma unroll
            for (int r = 0; r < 4; r++)
                pk[r] = bfbits(exp2f(sacc[j][r]));
            *(s4v*)&sPw[ln * LQP + j * 16 + qd * 4] = pk;
        }

        // O += P V: A=P[m=qrow], B=V^T[n=d]; ones-frag accumulates denominator.
        __builtin_amdgcn_s_setprio(1);
#pragma unroll
        for (int ks = 0; ks < 2; ks++) {
            // two b64 reads -> register-pair concat (no element inserts)
            const s4v p0 = *(const s4v*)&sPw[ln * LQP + ks * 32 + qd * 8];
            const s4v p1 = *(const s4v*)&sPw[ln * LQP + ks * 32 + qd * 8 + 4];
            const short8 ap = __builtin_shufflevector(p0, p1, 0, 1, 2, 3, 4, 5, 6, 7);
#pragma unroll
            for (int j = 0; j < 4; j++) {
                const int row = j * 16 + ln;
                const short8 bv_ = *(const short8*)
                    &sV[cur][row * 64 + (((ks * 4 + qd) ^ (row & 7)) << 3)];
                oacc[j] = MFMA16(ap, bv_, oacc[j]);
            }
            oacc[4] = MFMA16(ap, ones8, oacc[4]);
        }
        __builtin_amdgcn_s_setprio(0);
    }

    // denominator = col n=64 => lane (qd*16); broadcast within quad.
    const int b_ = bh >> 4, h_ = bh & 15;
#pragma unroll
    for (int r = 0; r < 4; r++) {
        const float l = __shfl(oacc[4][r], lane & 48, 64);
        const float inv = 1.0f / l;
        const int s_ = qt * 128 + wave * 16 + qd * 4 + r;
#pragma unroll
        for (int j = 0; j < 4; j++) {
            const int d_ = j * 16 + ln;
            ao_ws[(((size_t)(b_ * Sc + s_)) * Hc + h_) * DKc + d_] =
                __float2bfloat16(oacc[j][r] * inv);
        }
    }
}

// ---------------------------------------------------------------------------
// Output projection v11: BM=128, BN=64, BK=32 -> grid (16,32) = 512 blocks
// = 2 blocks/CU (v7's 256 = 1/CU left every barrier drain fully exposed;
// a second resident block overlaps it). Plain epilogue — no fusion (v10
// showed fused combine serializes the K-step critical path).
// Staging: 12 chunks/K-step (A:8, B:4); wave w stages A chunks 2w,2w+1 and
// B chunk w. Per wave 8 MFMA16 per K-step (64x32 tile, acc[4][2]).
// ---------------------------------------------------------------------------
__global__ __launch_bounds__(256) void out_gemm_kernel(
    const bf16* __restrict__ A, const bf16* __restrict__ Wo,
    const float* __restrict__ bo, float* __restrict__ out)
{
    constexpr int BM = 128, BN = 64, BK = 32;
    __shared__ __align__(16) bf16 sA[BM * BK];   // 8 KB
    __shared__ __align__(16) bf16 sB[BN * BK];   // 4 KB

    const int n0 = blockIdx.x * BN;
    const int m0 = blockIdx.y * BM;

    const int t = threadIdx.x;
    const int lane = t & 63;
    const int wave = t >> 6;
    const int ln = lane & 15;
    const int qd = lane >> 4;
    const int wm = (wave >> 1) * 64;
    const int wn = (wave & 1) * 32;

    const int gr = lane >> 2;              // row within 16-row chunk
    const int gc = (lane & 3) * 8;         // 0,8,16,24

    float4v acc[4][2];
#pragma unroll
    for (int i = 0; i < 4; i++)
#pragma unroll
        for (int j = 0; j < 2; j++) acc[i][j] = (float4v)0.0f;

    for (int kk = 0; kk < Dc; kk += BK) {
        __syncthreads();
#pragma unroll
        for (int cc = 0; cc < 2; cc++) {   // A chunks 2w, 2w+1
            const int c = wave * 2 + cc;
            GLD_LDS16(A + (size_t)(m0 + c * 16 + gr) * Dc + kk + gc, &sA[c * 512]);
        }
        GLD_LDS16(Wo + (size_t)(n0 + wave * 16 + gr) * Dc + kk + gc,
                  &sB[wave * 512]);
        __syncthreads();

        short8 af[4], wf[2];
#pragma unroll
        for (int i = 0; i < 4; i++)
            af[i] = *(const short8*)&sA[(wm + i * 16 + ln) * BK + qd * 8];
#pragma unroll
        for (int j = 0; j < 2; j++)
            wf[j] = *(const short8*)&sB[(wn + j * 16 + ln) * BK + qd * 8];
#pragma unroll
        for (int i = 0; i < 4; i++)
#pragma unroll
            for (int j = 0; j < 2; j++)
                acc[i][j] = MFMA16(af[i], wf[j], acc[i][j]);
    }

#pragma unroll
    for (int j = 0; j < 2; j++) {
        const int n = n0 + wn + j * 16 + ln;
        const float bias = bo[n];
#pragma unroll
        for (int i = 0; i < 4; i++) {
            const int mbase = m0 + wm + i * 16 + qd * 4;
#pragma unroll
            for (int r = 0; r < 4; r++) {
                const int m = mbase + r;
                out[(size_t)m * Dc + n] = acc[i][j][r] + bias;
            }
        }
    }
}

// ---------------------------------------------------------------------------
extern "C" void kernel_launch(void* const* d_in, const int* in_sizes, int n_in,
                              void* d_out, int out_size, void* d_ws, size_t ws_size,
                              hipStream_t stream)
{
    const float* x  = (const float*)d_in[0];
    const float* Wq = (const float*)d_in[1];
    const float* bq = (const float*)d_in[2];
    const float* Wk = (const float*)d_in[3];
    const float* bk = (const float*)d_in[4];
    const float* Wv = (const float*)d_in[5];
    const float* bv = (const float*)d_in[6];
    const float* Wo = (const float*)d_in[7];
    const float* bo = (const float*)d_in[8];
    float* out = (float*)d_out;

    bf16* base  = (bf16*)d_ws;
    bf16* q_ws  = base;                      // (b,h,s,d), pre-scaled
    bf16* k_ws  = base + 4 * MEG;            // (b,h,s,d)
    bf16* v_ws  = base + 8 * MEG;            // (b,h,d,s)  transposed
    bf16* ao_ws = base + 12 * MEG;           // (b,s,h,d) == (4096,1024)
    bf16* xb    = base + 16 * MEG;           // bf16 copies of inputs
    bf16* wqb   = base + 20 * MEG;
    bf16* wkb   = base + 21 * MEG;
    bf16* wvb   = base + 22 * MEG;
    bf16* wob   = base + 23 * MEG;

    cvt_kernel<<<dim3(4096), 256, 0, stream>>>(x, Wq, Wk, Wv, Wo, xb);
    qkv_gemm_kernel<<<dim3(24, 32), 256, 0, stream>>>(
        xb, wqb, bq, wkb, bk, wvb, bv, q_ws, k_ws, v_ws);
    attn_kernel<<<dim3(32, 16), 512, 0, stream>>>(q_ws, k_ws, v_ws, ao_ws);
    out_gemm_kernel<<<dim3(16, 32), 256, 0, stream>>>(ao_ws, wob, bo, out);
}

// Round 10
// 197.008 us; speedup vs baseline: 1.1463x; 1.0197x over previous
//
#include <hip/hip_runtime.h>
#include <hip/hip_bf16.h>

using bf16 = __hip_bfloat16;
typedef __attribute__((ext_vector_type(8))) short short8;
typedef __attribute__((ext_vector_type(4))) short s4v;
typedef __attribute__((ext_vector_type(4))) float float4v;
typedef __attribute__((ext_vector_type(4))) float f32x4;

#define MFMA16(a, b, c) __builtin_amdgcn_mfma_f32_16x16x32_bf16((a), (b), (c), 0, 0, 0)

// async global->LDS, 16B per lane, dest = wave-uniform base + lane*16
#define GLD_LDS16(g, l)                                            \
    __builtin_amdgcn_global_load_lds(                              \
        (const __attribute__((address_space(1))) void*)(g),        \
        (__attribute__((address_space(3))) void*)(l), 16, 0, 0)

constexpr int Bc = 2;
constexpr int Sc = 2048;
constexpr int Hc = 16;
constexpr int DKc = 64;
constexpr int Dc = 1024;
constexpr size_t MEG = 1024 * 1024;

union BFU { bf16 h; short s; };

__device__ inline short bfbits(float f) {
    BFU u; u.h = __float2bfloat16(f); return u.s;
}

__device__ inline short8 load_cvt8(const float* __restrict__ p) {
    f32x4 a = *(const f32x4*)p;
    f32x4 b = *(const f32x4*)(p + 4);
    short8 r;
    r[0] = bfbits(a[0]); r[1] = bfbits(a[1]); r[2] = bfbits(a[2]); r[3] = bfbits(a[3]);
    r[4] = bfbits(b[0]); r[5] = bfbits(b[1]); r[6] = bfbits(b[2]); r[7] = bfbits(b[3]);
    return r;
}

// ---------------------------------------------------------------------------
// One-shot fp32 -> bf16 conversion of x, Wq, Wk, Wv, Wo (8M elems) into ws.
// ---------------------------------------------------------------------------
__global__ __launch_bounds__(256) void cvt_kernel(
    const float* __restrict__ x, const float* __restrict__ Wq,
    const float* __restrict__ Wk, const float* __restrict__ Wv,
    const float* __restrict__ Wo, bf16* __restrict__ dst)
{
    const size_t i = ((size_t)blockIdx.x * 256 + threadIdx.x) * 8;
    const float* s;
    if      (i < 4 * MEG) s = x  + i;
    else if (i < 5 * MEG) s = Wq + (i - 4 * MEG);
    else if (i < 6 * MEG) s = Wk + (i - 5 * MEG);
    else if (i < 7 * MEG) s = Wv + (i - 6 * MEG);
    else                  s = Wo + (i - 7 * MEG);
    *(short8*)(dst + i) = load_cvt8(s);
}

// ---------------------------------------------------------------------------
// Fused QKV projection v12: attn-style K-loop — double-buffered LDS (2x16KB),
// ONE barrier per K-step, prefetch-after-barrier (loads get a full compute
// phase to land; the old m97 2-barrier loop exposed a zero-hidden vmcnt
// drain 32x per block). XOR-swizzled staging: slot = qd ^ ((row>>1)&3) --
// 16 lanes spread over 8 bank-groups, 2-way (free) vs linear's 8-way.
// grid (24, 32): sel = bx>>3. Q pre-scaled by (1/8)*log2e. V^T packed 8B.
// ---------------------------------------------------------------------------
__global__ __launch_bounds__(256) void qkv_gemm_kernel(
    const bf16* __restrict__ x,
    const bf16* __restrict__ Wq, const float* __restrict__ bq,
    const bf16* __restrict__ Wk, const float* __restrict__ bk,
    const bf16* __restrict__ Wv, const float* __restrict__ bv,
    bf16* __restrict__ q_ws, bf16* __restrict__ k_ws, bf16* __restrict__ v_ws)
{
    constexpr int BM = 128, BN = 128, BK = 32, NT = Dc / BK;
    __shared__ __align__(16) bf16 sA[2][BM * BK];
    __shared__ __align__(16) bf16 sB[2][BN * BK];

    const int bx = blockIdx.x;
    const int sel = bx >> 3;               // 0=Q 1=K 2=V
    const int n0 = (bx & 7) * BN;
    const int m0 = blockIdx.y * BM;

    const bf16* __restrict__ Wsel = (sel == 0) ? Wq : ((sel == 1) ? Wk : Wv);
    const float* __restrict__ bsel = (sel == 0) ? bq : ((sel == 1) ? bk : bv);

    const int t = threadIdx.x;
    const int lane = t & 63;
    const int wave = t >> 6;
    const int ln = lane & 15;
    const int qd = lane >> 4;
    const int wm = (wave >> 1) * 64;
    const int wn = (wave & 1) * 64;

    const int rloc = lane >> 2;            // 0..15: row within 16-row chunk
    const int blk = lane & 3;              // 16B-slot within row
    const int gb = (blk ^ ((rloc >> 1) & 3)) * 8;   // swizzled global col
    const int xr = (qd ^ ((ln >> 1) & 3)) << 3;     // swizzled read offset

    auto stage = [&](int buf, int kk) {
#pragma unroll
        for (int cc = 0; cc < 4; cc++) {
            const int cid = wave * 4 + cc;             // 0..15
            if (cid < 8)
                GLD_LDS16(x + (size_t)(m0 + cid * 16 + rloc) * Dc + kk + gb,
                          &sA[buf][cid * 512]);
            else
                GLD_LDS16(Wsel + (size_t)(n0 + (cid - 8) * 16 + rloc) * Dc + kk + gb,
                          &sB[buf][(cid - 8) * 512]);
        }
    };

    float4v acc[4][4];
#pragma unroll
    for (int i = 0; i < 4; i++)
#pragma unroll
        for (int j = 0; j < 4; j++) acc[i][j] = (float4v)0.0f;

    stage(0, 0);
    for (int tt = 0; tt < NT; tt++) {
        const int cur = tt & 1;
        __syncthreads();                   // drains vmcnt: buf[cur] ready
        if (tt + 1 < NT) stage(cur ^ 1, (tt + 1) * BK);

        short8 af[4], wf[4];
#pragma unroll
        for (int i = 0; i < 4; i++)
            af[i] = *(const short8*)&sA[cur][(wm + i * 16 + ln) * BK + xr];
#pragma unroll
        for (int j = 0; j < 4; j++)
            wf[j] = *(const short8*)&sB[cur][(wn + j * 16 + ln) * BK + xr];
#pragma unroll
        for (int i = 0; i < 4; i++)
#pragma unroll
            for (int j = 0; j < 4; j++)
                acc[i][j] = MFMA16(af[i], wf[j], acc[i][j]);
    }

    constexpr float QSCALE = 0.125f * 1.44269504088896f;

#pragma unroll
    for (int j = 0; j < 4; j++) {
        const int n = n0 + wn + j * 16 + ln;
        const float bias = bsel[n];
        const int h_ = n >> 6, d_ = n & 63;
#pragma unroll
        for (int i = 0; i < 4; i++) {
            const int mbase = m0 + wm + i * 16 + qd * 4;
            if (sel == 2) {                // V^T: 4 s-contiguous -> one 8B store
                const int b_ = mbase >> 11, s_ = mbase & 2047;
                s4v pk;
#pragma unroll
                for (int r = 0; r < 4; r++)
                    pk[r] = bfbits(acc[i][j][r] + bias);
                *(s4v*)&v_ws[(((size_t)(b_ * Hc + h_)) * DKc + d_) * Sc + s_] = pk;
            } else {
#pragma unroll
                for (int r = 0; r < 4; r++) {
                    const int m = mbase + r;
                    const int b_ = m >> 11, s_ = m & 2047;
                    float v = acc[i][j][r] + bias;
                    if (sel == 0) v *= QSCALE;
                    const bf16 o = __float2bfloat16(v);
                    if (sel == 0)
                        q_ws[(((size_t)(b_ * Hc + h_)) * Sc + s_) * DKc + d_] = o;
                    else
                        k_ws[(((size_t)(b_ * Hc + h_)) * Sc + s_) * DKc + d_] = o;
                }
            }
        }
    }
}

// ---------------------------------------------------------------------------
// Flash attention v7 (UNCHANGED — proven 63.7-65.6 us, 0 bank conflicts):
// 8 waves x 16 q-rows, Q in registers, sP stride 76 (conflict-free),
// xor-swizzled async dbuf K/V, ONE barrier/ktile, swapped-operand QK^T,
// ones-column denominator, setprio around MFMA clusters. grid (32,16), 512.
// ---------------------------------------------------------------------------
__global__ __launch_bounds__(512, 4) void attn_kernel(
    const bf16* __restrict__ q_ws, const bf16* __restrict__ k_ws,
    const bf16* __restrict__ v_ws, bf16* __restrict__ ao_ws)
{
    constexpr int LQP = 76;  // short row stride for sP (152 B, conflict-free)
    __shared__ __align__(16) bf16 sK[2][64 * 64];    // swizzled dbuf
    __shared__ __align__(16) bf16 sV[2][64 * 64];    // V^T [d][key], swizzled dbuf
    __shared__ __align__(16) short sP[8][16 * LQP];  // per-wave P [qrow][key]

    const int bh = blockIdx.x;
    const int qt = blockIdx.y;
    const int t = threadIdx.x;
    const int lane = t & 63;
    const int wave = t >> 6;               // 0..7
    const int ln = lane & 15;
    const int qd = lane >> 4;
    short* const sPw = sP[wave];

    const bf16* __restrict__ Qbase = q_ws + (size_t)bh * Sc * DKc + qt * 128 * DKc;
    const bf16* __restrict__ Kbase = k_ws + (size_t)bh * Sc * DKc;
    const bf16* __restrict__ Vbase = v_ws + (size_t)bh * DKc * Sc;

    const int rloc = lane >> 3;            // 0..7 row within 8-row chunk
    const int blk = lane & 7;              // LDS 16B-block index

    // Q B-frags direct global->register, loop-invariant (8 VGPRs).
    // lane holds Q[qrow = wave*16 + ln][k = ks*32 + qd*8 .. +7]
    short8 qf[2];
#pragma unroll
    for (int ks = 0; ks < 2; ks++)
        qf[ks] = *(const short8*)
            (Qbase + (size_t)(wave * 16 + ln) * DKc + ks * 32 + qd * 8);

    {   // stage K/V tile 0 async: 8 chunks each, one per wave
        const int row = wave * 8 + rloc;
        const int gb = blk ^ (row & 7);
        GLD_LDS16(Kbase + (size_t)row * DKc + gb * 8, &sK[0][wave * 512]);
        GLD_LDS16(Vbase + (size_t)row * Sc + gb * 8, &sV[0][wave * 512]);
    }

    // constant ones B-frag: B[n=64+ln][k]=1 iff ln==0 (denominator column)
    short8 ones8;
    {
        const short ob = (ln == 0) ? (short)0x3F80 : (short)0;
#pragma unroll
        for (int i = 0; i < 8; i++) ones8[i] = ob;
    }

    float4v oacc[5];
#pragma unroll
    for (int j = 0; j < 5; j++) oacc[j] = (float4v)0.0f;

    for (int kt = 0; kt < Sc / 64; kt++) {
        const int cur = kt & 1;
        __syncthreads();   // drains vmcnt: buf[cur] ready; prior reads done
        if (kt + 1 < Sc / 64) {    // prefetch next tile into the other buffer
            const int nxt = (kt + 1) & 1;
            const int row = wave * 8 + rloc;
            const int gb = blk ^ (row & 7);
            GLD_LDS16(Kbase + (size_t)((kt + 1) * 64 + row) * DKc + gb * 8,
                      &sK[nxt][wave * 512]);
            GLD_LDS16(Vbase + (size_t)row * Sc + (kt + 1) * 64 + gb * 8,
                      &sV[nxt][wave * 512]);
        }

        // S^T = K Q^T: A=K[m=key], B=Q[n=qrow]; C col=qrow(ln), row=key(qd*4+r)
        float4v sacc[4];
#pragma unroll
        for (int j = 0; j < 4; j++) sacc[j] = (float4v)0.0f;
        __builtin_amdgcn_s_setprio(1);
#pragma unroll
        for (int ks = 0; ks < 2; ks++) {
#pragma unroll
            for (int j = 0; j < 4; j++) {
                const int row = j * 16 + ln;
                const short8 ak = *(const short8*)
                    &sK[cur][row * 64 + (((ks * 4 + qd) ^ (row & 7)) << 3)];
                sacc[j] = MFMA16(ak, qf[ks], sacc[j]);
            }
        }
        __builtin_amdgcn_s_setprio(0);

        // P = exp2(S^T) -> sP [qrow][key]: lane holds qrow=ln, keys 4-contig.
#pragma unroll
        for (int j = 0; j < 4; j++) {
            s4v pk;
#pragma unroll
            for (int r = 0; r < 4; r++)
                pk[r] = bfbits(exp2f(sacc[j][r]));
            *(s4v*)&sPw[ln * LQP + j * 16 + qd * 4] = pk;
        }

        // O += P V: A=P[m=qrow], B=V^T[n=d]; ones-frag accumulates denominator.
        __builtin_amdgcn_s_setprio(1);
#pragma unroll
        for (int ks = 0; ks < 2; ks++) {
            // two b64 reads -> register-pair concat (no element inserts)
            const s4v p0 = *(const s4v*)&sPw[ln * LQP + ks * 32 + qd * 8];
            const s4v p1 = *(const s4v*)&sPw[ln * LQP + ks * 32 + qd * 8 + 4];
            const short8 ap = __builtin_shufflevector(p0, p1, 0, 1, 2, 3, 4, 5, 6, 7);
#pragma unroll
            for (int j = 0; j < 4; j++) {
                const int row = j * 16 + ln;
                const short8 bv_ = *(const short8*)
                    &sV[cur][row * 64 + (((ks * 4 + qd) ^ (row & 7)) << 3)];
                oacc[j] = MFMA16(ap, bv_, oacc[j]);
            }
            oacc[4] = MFMA16(ap, ones8, oacc[4]);
        }
        __builtin_amdgcn_s_setprio(0);
    }

    // denominator = col n=64 => lane (qd*16); broadcast within quad.
    const int b_ = bh >> 4, h_ = bh & 15;
#pragma unroll
    for (int r = 0; r < 4; r++) {
        const float l = __shfl(oacc[4][r], lane & 48, 64);
        const float inv = 1.0f / l;
        const int s_ = qt * 128 + wave * 16 + qd * 4 + r;
#pragma unroll
        for (int j = 0; j < 4; j++) {
            const int d_ = j * 16 + ln;
            ao_ws[(((size_t)(b_ * Sc + s_)) * Hc + h_) * DKc + d_] =
                __float2bfloat16(oacc[j][r] * inv);
        }
    }
}

// ---------------------------------------------------------------------------
// Output projection v12: v7 geometry (BM=BN=128, grid (8,32) — BN=64 was
// measured harmful in R9), with the attn-style single-barrier dbuf K-loop
// and swizzled staging (same as qkv v12). At 1 block/CU the halved,
// latency-hidden drains attack exactly the exposed-stall diagnosis.
// ---------------------------------------------------------------------------
__global__ __launch_bounds__(256) void out_gemm_kernel(
    const bf16* __restrict__ A, const bf16* __restrict__ Wo,
    const float* __restrict__ bo, float* __restrict__ out)
{
    constexpr int BM = 128, BN = 128, BK = 32, NT = Dc / BK;
    __shared__ __align__(16) bf16 sA[2][BM * BK];
    __shared__ __align__(16) bf16 sB[2][BN * BK];

    const int n0 = blockIdx.x * BN;
    const int m0 = blockIdx.y * BM;

    const int t = threadIdx.x;
    const int lane = t & 63;
    const int wave = t >> 6;
    const int ln = lane & 15;
    const int qd = lane >> 4;
    const int wm = (wave >> 1) * 64;
    const int wn = (wave & 1) * 64;

    const int rloc = lane >> 2;            // 0..15: row within 16-row chunk
    const int blk = lane & 3;              // 16B-slot within row
    const int gb = (blk ^ ((rloc >> 1) & 3)) * 8;
    const int xr = (qd ^ ((ln >> 1) & 3)) << 3;

    auto stage = [&](int buf, int kk) {
#pragma unroll
        for (int cc = 0; cc < 4; cc++) {
            const int cid = wave * 4 + cc;             // 0..15
            if (cid < 8)
                GLD_LDS16(A + (size_t)(m0 + cid * 16 + rloc) * Dc + kk + gb,
                          &sA[buf][cid * 512]);
            else
                GLD_LDS16(Wo + (size_t)(n0 + (cid - 8) * 16 + rloc) * Dc + kk + gb,
                          &sB[buf][(cid - 8) * 512]);
        }
    };

    float4v acc[4][4];
#pragma unroll
    for (int i = 0; i < 4; i++)
#pragma unroll
        for (int j = 0; j < 4; j++) acc[i][j] = (float4v)0.0f;

    stage(0, 0);
    for (int tt = 0; tt < NT; tt++) {
        const int cur = tt & 1;
        __syncthreads();                   // drains vmcnt: buf[cur] ready
        if (tt + 1 < NT) stage(cur ^ 1, (tt + 1) * BK);

        short8 af[4], wf[4];
#pragma unroll
        for (int i = 0; i < 4; i++)
            af[i] = *(const short8*)&sA[cur][(wm + i * 16 + ln) * BK + xr];
#pragma unroll
        for (int j = 0; j < 4; j++)
            wf[j] = *(const short8*)&sB[cur][(wn + j * 16 + ln) * BK + xr];
#pragma unroll
        for (int i = 0; i < 4; i++)
#pragma unroll
            for (int j = 0; j < 4; j++)
                acc[i][j] = MFMA16(af[i], wf[j], acc[i][j]);
    }

#pragma unroll
    for (int j = 0; j < 4; j++) {
        const int n = n0 + wn + j * 16 + ln;
        const float bias = bo[n];
#pragma unroll
        for (int i = 0; i < 4; i++) {
            const int mbase = m0 + wm + i * 16 + qd * 4;
#pragma unroll
            for (int r = 0; r < 4; r++) {
                const int m = mbase + r;
                out[(size_t)m * Dc + n] = acc[i][j][r] + bias;
            }
        }
    }
}

// ---------------------------------------------------------------------------
extern "C" void kernel_launch(void* const* d_in, const int* in_sizes, int n_in,
                              void* d_out, int out_size, void* d_ws, size_t ws_size,
                              hipStream_t stream)
{
    const float* x  = (const float*)d_in[0];
    const float* Wq = (const float*)d_in[1];
    const float* bq = (const float*)d_in[2];
    const float* Wk = (const float*)d_in[3];
    const float* bk = (const float*)d_in[4];
    const float* Wv = (const float*)d_in[5];
    const float* bv = (const float*)d_in[6];
    const float* Wo = (const float*)d_in[7];
    const float* bo = (const float*)d_in[8];
    float* out = (float*)d_out;

    bf16* base  = (bf16*)d_ws;
    bf16* q_ws  = base;                      // (b,h,s,d), pre-scaled
    bf16* k_ws  = base + 4 * MEG;            // (b,h,s,d)
    bf16* v_ws  = base + 8 * MEG;            // (b,h,d,s)  transposed
    bf16* ao_ws = base + 12 * MEG;           // (b,s,h,d) == (4096,1024)
    bf16* xb    = base + 16 * MEG;           // bf16 copies of inputs
    bf16* wqb   = base + 20 * MEG;
    bf16* wkb   = base + 21 * MEG;
    bf16* wvb   = base + 22 * MEG;
    bf16* wob   = base + 23 * MEG;

    cvt_kernel<<<dim3(4096), 256, 0, stream>>>(x, Wq, Wk, Wv, Wo, xb);
    qkv_gemm_kernel<<<dim3(24, 32), 256, 0, stream>>>(
        xb, wqb, bq, wkb, bk, wvb, bv, q_ws, k_ws, v_ws);
    attn_kernel<<<dim3(32, 16), 512, 0, stream>>>(q_ws, k_ws, v_ws, ao_ws);
    out_gemm_kernel<<<dim3(8, 32), 256, 0, stream>>>(ao_ws, wob, bo, out);
}